// Round 5
// baseline (140.259 us; speedup 1.0000x reference)
//
#include <hip/hip_runtime.h>
#include <cstdint>
#include <cmath>

#define B_ROWS 256
#define V_COLS 128000
#define CHUNKS 8
#define CHUNK_ELEMS (V_COLS / CHUNKS)   // 16000
#define CHUNK_QUADS (CHUNK_ELEMS / 4)   // 4000
#define ATHREADS 256
#define AWAVES (ATHREADS / 64)
#define LN2F 0.69314718055994530942f

// ws layout (floats): partials[row][chunk][6] then finals[row][2]
#define P_STRIDE 6
#define FIN_OFF (B_ROWS * CHUNKS * P_STRIDE)

__device__ __forceinline__ uint32_t rotl32(uint32_t x, uint32_t d) {
  return __builtin_amdgcn_alignbit(x, x, 32u - d);
}

// threefry2x32 key (0,42), XOR of outputs (JAX partitionable threefry).
__device__ __forceinline__ uint32_t threefry_xor(uint32_t x0, uint32_t x1) {
  const uint32_t k0 = 0u;
  const uint32_t k1 = 42u;
  const uint32_t k2 = 0x1BD11BDAu ^ k0 ^ k1;
  x0 += k0; x1 += k1;
#define TF_RND(r) { x0 += x1; x1 = rotl32(x1, (r)); x1 ^= x0; }
  TF_RND(13) TF_RND(15) TF_RND(26) TF_RND(6)
  x0 += k1; x1 += k2 + 1u;
  TF_RND(17) TF_RND(29) TF_RND(16) TF_RND(24)
  x0 += k2; x1 += k0 + 2u;
  TF_RND(13) TF_RND(15) TF_RND(26) TF_RND(6)
  x0 += k0; x1 += k1 + 3u;
  TF_RND(17) TF_RND(29) TF_RND(16) TF_RND(24)
  x0 += k1; x1 += k2 + 4u;
  TF_RND(13) TF_RND(15) TF_RND(26) TF_RND(6)
  x0 += k2; x1 += k0 + 5u;
#undef TF_RND
  return x0 ^ x1;
}

// gumbel = -LN2F * gumbel_l2(bits)  (caller folds into fma)
__device__ __forceinline__ float gumbel_l2(uint32_t bits) {
  uint32_t ub = (bits >> 9) | 0x3f800000u;
  float f = __uint_as_float(ub) - 1.0f;
  float u = fmaxf(f, 1.17549435e-38f);
  const float l1 = __log2f(u);
  const float nl = -LN2F * l1;
  return __log2f(nl);
}

// ---------------- Kernel A: per-chunk partials ----------------
__global__ __launch_bounds__(ATHREADS) void partial_kernel(
    const float* __restrict__ logits,
    const float* __restrict__ temps,
    float* __restrict__ ws) {
  const int bx = blockIdx.x;
  const int b = bx >> 3;          // row
  const int chunk = bx & (CHUNKS - 1);
  const int tid = threadIdx.x;
  const float t = temps[b];
  const float inv_t = (t == 0.0f) ? 1.0f : (1.0f / t);
  const float* __restrict__ row = logits + (size_t)b * V_COLS;
  const int qbase = chunk * CHUNK_QUADS;     // quad offset within row

  float gmax = -INFINITY; int gidx = 0;
  float smax = -INFINITY; int sidx = 0;
  float m = -INFINITY, s = 0.0f;

  const uint32_t cbase = (uint32_t)b * (uint32_t)V_COLS + (uint32_t)(qbase * 4);

  if (t != 0.0f) {
    for (int i = tid; i < CHUNK_QUADS; i += ATHREADS) {
      const float4 x4 = reinterpret_cast<const float4*>(row)[qbase + i];
      const uint32_t c0 = cbase + (uint32_t)(i * 4);
      const int v0 = (qbase + i) * 4;
      const float sx0 = x4.x * inv_t;
      const float sx1 = x4.y * inv_t;
      const float sx2 = x4.z * inv_t;
      const float sx3 = x4.w * inv_t;
      {
        const float c = fmaf(-LN2F, gumbel_l2(threefry_xor(0u, c0 + 0u)), sx0);
        if (c > smax) { smax = c; sidx = v0 + 0; }
      }
      {
        const float c = fmaf(-LN2F, gumbel_l2(threefry_xor(0u, c0 + 1u)), sx1);
        if (c > smax) { smax = c; sidx = v0 + 1; }
      }
      {
        const float c = fmaf(-LN2F, gumbel_l2(threefry_xor(0u, c0 + 2u)), sx2);
        if (c > smax) { smax = c; sidx = v0 + 2; }
      }
      {
        const float c = fmaf(-LN2F, gumbel_l2(threefry_xor(0u, c0 + 3u)), sx3);
        if (c > smax) { smax = c; sidx = v0 + 3; }
      }
      const float mx4 = fmaxf(fmaxf(x4.x, x4.y), fmaxf(x4.z, x4.w));
      gmax = fmaxf(gmax, mx4);
      const float mn = fmaxf(m, mx4 * inv_t);
      s = fmaf(s, __expf(m - mn),
               __expf(sx0 - mn) + __expf(sx1 - mn) +
               __expf(sx2 - mn) + __expf(sx3 - mn));
      m = mn;
    }
  } else {
    for (int i = tid; i < CHUNK_QUADS; i += ATHREADS) {
      const float4 x4 = reinterpret_cast<const float4*>(row)[qbase + i];
      const int v0 = (qbase + i) * 4;
      if (x4.x > gmax) { gmax = x4.x; gidx = v0 + 0; }
      if (x4.y > gmax) { gmax = x4.y; gidx = v0 + 1; }
      if (x4.z > gmax) { gmax = x4.z; gidx = v0 + 2; }
      if (x4.w > gmax) { gmax = x4.w; gidx = v0 + 3; }
      const float mx4 = fmaxf(fmaxf(x4.x, x4.y), fmaxf(x4.z, x4.w));
      const float mn = fmaxf(m, mx4);
      s = fmaf(s, __expf(m - mn),
               __expf(x4.x - mn) + __expf(x4.y - mn) +
               __expf(x4.z - mn) + __expf(x4.w - mn));
      m = mn;
    }
  }

  // wave butterfly reduce; ties -> lower index
#pragma unroll
  for (int off = 32; off > 0; off >>= 1) {
    float ov = __shfl_xor(gmax, off);
    int   oi = __shfl_xor(gidx, off);
    if (ov > gmax || (ov == gmax && oi < gidx)) { gmax = ov; gidx = oi; }
    float osv = __shfl_xor(smax, off);
    int   osi = __shfl_xor(sidx, off);
    if (osv > smax || (osv == smax && osi < sidx)) { smax = osv; sidx = osi; }
    float om = __shfl_xor(m, off);
    float os = __shfl_xor(s, off);
    float mn = fmaxf(m, om);
    s = fmaf(s, __expf(m - mn), os * __expf(om - mn));
    m = mn;
  }

  __shared__ float lds_gv[AWAVES]; __shared__ int lds_gi[AWAVES];
  __shared__ float lds_sv[AWAVES]; __shared__ int lds_si[AWAVES];
  __shared__ float lds_m[AWAVES];  __shared__ float lds_s[AWAVES];
  const int wid = tid >> 6;
  if ((tid & 63) == 0) {
    lds_gv[wid] = gmax; lds_gi[wid] = gidx;
    lds_sv[wid] = smax; lds_si[wid] = sidx;
    lds_m[wid] = m;     lds_s[wid] = s;
  }
  __syncthreads();
  if (tid == 0) {
    float Gv = lds_gv[0]; int Gi = lds_gi[0];
    float Sv = lds_sv[0]; int Si = lds_si[0];
    float M = lds_m[0];   float S = lds_s[0];
#pragma unroll
    for (int w = 1; w < AWAVES; ++w) {
      float ov = lds_gv[w]; int oi = lds_gi[w];
      if (ov > Gv || (ov == Gv && oi < Gi)) { Gv = ov; Gi = oi; }
      float osv = lds_sv[w]; int osi = lds_si[w];
      if (osv > Sv || (osv == Sv && osi < Si)) { Sv = osv; Si = osi; }
      float om = lds_m[w]; float os = lds_s[w];
      float mn = fmaxf(M, om);
      S = fmaf(S, __expf(M - mn), os * __expf(om - mn));
      M = mn;
    }
    float* p = ws + (size_t)(b * CHUNKS + chunk) * P_STRIDE;
    p[0] = Gv; p[1] = __int_as_float(Gi);
    p[2] = Sv; p[3] = __int_as_float(Si);
    p[4] = M;  p[5] = S;
  }
}

// ---------------- Kernel B: per-row merge + token ----------------
__global__ __launch_bounds__(B_ROWS) void finalize_kernel(
    const float* __restrict__ temps,
    float* __restrict__ ws,
    float* __restrict__ out) {
  const int r = threadIdx.x;
  const float t = temps[r];
  const float* p = ws + (size_t)r * CHUNKS * P_STRIDE;
  float Gv = -INFINITY; int Gi = 0;
  float Sv = -INFINITY; int Si = 0;
  float M = -INFINITY;  float S = 0.0f;
#pragma unroll
  for (int c = 0; c < CHUNKS; ++c) {
    const float* q = p + c * P_STRIDE;
    float ov = q[0]; int oi = __float_as_int(q[1]);
    if (ov > Gv) { Gv = ov; Gi = oi; }         // ascending chunk order => first index wins
    float osv = q[2]; int osi = __float_as_int(q[3]);
    if (osv > Sv) { Sv = osv; Si = osi; }
    float om = q[4]; float os = q[5];
    float mn = fmaxf(M, om);
    S = fmaf(S, __expf(M - mn), os * __expf(om - mn));
    M = mn;
  }
  out[r] = (float)((t == 0.0f) ? Gi : Si);
  ws[FIN_OFF + 2 * r]     = M;
  ws[FIN_OFF + 2 * r + 1] = 1.0f / S;
}

// ---------------- Kernel C: probs streaming ----------------
__global__ __launch_bounds__(ATHREADS) void probs_kernel(
    const float* __restrict__ logits,
    const float* __restrict__ temps,
    const float* __restrict__ ws,
    float* __restrict__ out) {
  const int bx = blockIdx.x;
  const int b = bx >> 3;
  const int chunk = bx & (CHUNKS - 1);
  const int tid = threadIdx.x;
  const float t = temps[b];
  const float inv_t = (t == 0.0f) ? 1.0f : (1.0f / t);
  const float M = ws[FIN_OFF + 2 * b];
  const float invS = ws[FIN_OFF + 2 * b + 1];
  const float* __restrict__ row = logits + (size_t)b * V_COLS;
  float* __restrict__ prow = out + B_ROWS + (size_t)b * V_COLS;
  const int qbase = chunk * CHUNK_QUADS;

  for (int i = tid; i < CHUNK_QUADS; i += ATHREADS) {
    const float4 x4 = reinterpret_cast<const float4*>(row)[qbase + i];
    float4 p4;
    p4.x = __expf(fmaf(x4.x, inv_t, -M)) * invS;
    p4.y = __expf(fmaf(x4.y, inv_t, -M)) * invS;
    p4.z = __expf(fmaf(x4.z, inv_t, -M)) * invS;
    p4.w = __expf(fmaf(x4.w, inv_t, -M)) * invS;
    reinterpret_cast<float4*>(prow)[qbase + i] = p4;
  }
}

extern "C" void kernel_launch(void* const* d_in, const int* in_sizes, int n_in,
                              void* d_out, int out_size, void* d_ws, size_t ws_size,
                              hipStream_t stream) {
  const float* logits = (const float*)d_in[0];
  const float* temps  = (const float*)d_in[1];
  float* out = (float*)d_out;
  float* ws  = (float*)d_ws;
  partial_kernel<<<B_ROWS * CHUNKS, ATHREADS, 0, stream>>>(logits, temps, ws);
  finalize_kernel<<<1, B_ROWS, 0, stream>>>(temps, ws, out);
  probs_kernel<<<B_ROWS * CHUNKS, ATHREADS, 0, stream>>>(logits, temps, ws, out);
}

// Round 6
// 119.592 us; speedup vs baseline: 1.1728x; 1.1728x over previous
//
#include <hip/hip_runtime.h>
#include <cstdint>
#include <cmath>

#define B_ROWS 256
#define V_COLS 128000
#define CHUNKS 25
#define CHUNK_QUADS 1280           // V_COLS/4/CHUNKS, exactly 5 per thread
#define ATHREADS 256
#define AWAVES 4
#define QPT 5
#define ELEMS_PT 20
#define LN2F 0.69314718055994530942f

// ws floats: partials[row][chunk][4] = (val, idx, M, S), then finals[row][2]
#define P_STRIDE 4
#define FIN_OFF (B_ROWS * CHUNKS * P_STRIDE)   // 25600

__device__ __forceinline__ uint32_t rotl32(uint32_t x, uint32_t d) {
  return __builtin_amdgcn_alignbit(x, x, 32u - d);
}

// threefry2x32 key (0,42), XOR of outputs (JAX partitionable threefry).
__device__ __forceinline__ uint32_t threefry_xor(uint32_t x0, uint32_t x1) {
  const uint32_t k0 = 0u;
  const uint32_t k1 = 42u;
  const uint32_t k2 = 0x1BD11BDAu ^ k0 ^ k1;
  x0 += k0; x1 += k1;
#define TF_RND(r) { x0 += x1; x1 = rotl32(x1, (r)); x1 ^= x0; }
  TF_RND(13) TF_RND(15) TF_RND(26) TF_RND(6)
  x0 += k1; x1 += k2 + 1u;
  TF_RND(17) TF_RND(29) TF_RND(16) TF_RND(24)
  x0 += k2; x1 += k0 + 2u;
  TF_RND(13) TF_RND(15) TF_RND(26) TF_RND(6)
  x0 += k0; x1 += k1 + 3u;
  TF_RND(17) TF_RND(29) TF_RND(16) TF_RND(24)
  x0 += k1; x1 += k2 + 4u;
  TF_RND(13) TF_RND(15) TF_RND(26) TF_RND(6)
  x0 += k2; x1 += k0 + 5u;
#undef TF_RND
  return x0 ^ x1;
}

// gumbel = -LN2F * gumbel_l2(bits); caller folds into fma with sx
__device__ __forceinline__ float gumbel_l2(uint32_t bits) {
  uint32_t ub = (bits >> 9) | 0x3f800000u;
  float f = __uint_as_float(ub) - 1.0f;
  float u = fmaxf(f, 1.17549435e-38f);
  const float l1 = __log2f(u);
  const float nl = -LN2F * l1;
  return __log2f(nl);
}

// ---------------- Kernel A: per-chunk partials (5 quads/thread, unrolled) ---
__global__ __launch_bounds__(ATHREADS, 4) void partial_kernel(
    const float* __restrict__ logits,
    const float* __restrict__ temps,
    float* __restrict__ ws) {
  const uint32_t bx = blockIdx.x;
  const uint32_t b = bx / CHUNKS;           // SALU magic-mul
  const uint32_t chunk = bx - b * CHUNKS;
  const int tid = threadIdx.x;
  const float t = temps[b];
  const float inv_t = (t == 0.0f) ? 1.0f : (1.0f / t);
  const float* __restrict__ row = logits + (size_t)b * V_COLS;
  const int q0 = (int)chunk * CHUNK_QUADS + tid;

  // straight-line: load all 5 quads up front
  float4 xq[QPT];
#pragma unroll
  for (int j = 0; j < QPT; ++j)
    xq[j] = reinterpret_cast<const float4*>(row)[q0 + j * ATHREADS];

  float sx[ELEMS_PT];
#pragma unroll
  for (int j = 0; j < QPT; ++j) {
    sx[4 * j + 0] = xq[j].x * inv_t;
    sx[4 * j + 1] = xq[j].y * inv_t;
    sx[4 * j + 2] = xq[j].z * inv_t;
    sx[4 * j + 3] = xq[j].w * inv_t;
  }

  // thread max of sx (no exp chain), then plain exp-sum against it
  float mthr = sx[0];
#pragma unroll
  for (int k = 1; k < ELEMS_PT; ++k) mthr = fmaxf(mthr, sx[k]);

  float s = 0.0f;
#pragma unroll
  for (int k = 0; k < ELEMS_PT; ++k) s += __expf(sx[k] - mthr);

  // argmax candidate: gumbel (t!=0) or raw logits (t==0, sx==x bitwise)
  float av = -INFINITY; int ai = 0;
  const int v0 = q0 * 4;
  if (t != 0.0f) {
    const uint32_t cb = b * (uint32_t)V_COLS + (uint32_t)v0;
#pragma unroll
    for (int j = 0; j < QPT; ++j) {
#pragma unroll
      for (int k = 0; k < 4; ++k) {
        const float c = fmaf(-LN2F,
            gumbel_l2(threefry_xor(0u, cb + (uint32_t)(j * 1024 + k))),
            sx[4 * j + k]);
        // strict >, ascending order => first index wins on tie
        const bool up = c > av;
        av = up ? c : av;
        ai = up ? (v0 + j * 1024 + k) : ai;
      }
    }
  } else {
#pragma unroll
    for (int j = 0; j < QPT; ++j) {
#pragma unroll
      for (int k = 0; k < 4; ++k) {
        const float x = sx[4 * j + k];
        const bool up = x > av;
        av = up ? x : av;
        ai = up ? (v0 + j * 1024 + k) : ai;
      }
    }
  }

  // wave butterfly reduce; ties -> lower index
  float m = mthr;
#pragma unroll
  for (int off = 32; off > 0; off >>= 1) {
    float ov = __shfl_xor(av, off);
    int   oi = __shfl_xor(ai, off);
    if (ov > av || (ov == av && oi < ai)) { av = ov; ai = oi; }
    float om = __shfl_xor(m, off);
    float os = __shfl_xor(s, off);
    float mn = fmaxf(m, om);
    s = fmaf(s, __expf(m - mn), os * __expf(om - mn));
    m = mn;
  }

  __shared__ float lds_av[AWAVES]; __shared__ int lds_ai[AWAVES];
  __shared__ float lds_m[AWAVES];  __shared__ float lds_s[AWAVES];
  const int wid = tid >> 6;
  if ((tid & 63) == 0) {
    lds_av[wid] = av; lds_ai[wid] = ai;
    lds_m[wid] = m;   lds_s[wid] = s;
  }
  __syncthreads();
  if (tid == 0) {
    float Av = lds_av[0]; int Ai = lds_ai[0];
    float M = lds_m[0];   float S = lds_s[0];
#pragma unroll
    for (int w = 1; w < AWAVES; ++w) {
      float ov = lds_av[w]; int oi = lds_ai[w];
      if (ov > Av || (ov == Av && oi < Ai)) { Av = ov; Ai = oi; }
      float om = lds_m[w]; float os = lds_s[w];
      float mn = fmaxf(M, om);
      S = fmaf(S, __expf(M - mn), os * __expf(om - mn));
      M = mn;
    }
    float* p = ws + (size_t)(b * CHUNKS + chunk) * P_STRIDE;
    p[0] = Av; p[1] = __int_as_float(Ai);
    p[2] = M;  p[3] = S;
  }
}

// ---------------- Kernel B: per-row merge + token ----------------
__global__ __launch_bounds__(B_ROWS) void finalize_kernel(
    const float* __restrict__ temps,
    float* __restrict__ ws,
    float* __restrict__ out) {
  const int r = threadIdx.x;
  const float* p = ws + (size_t)r * CHUNKS * P_STRIDE;
  float Av = -INFINITY; int Ai = 0;
  float M = -INFINITY;  float S = 0.0f;
#pragma unroll
  for (int c = 0; c < CHUNKS; ++c) {
    const float* q = p + c * P_STRIDE;
    float ov = q[0]; int oi = __float_as_int(q[1]);
    if (ov > Av) { Av = ov; Ai = oi; }   // ascending chunks => first index wins
    float om = q[2]; float os = q[3];
    float mn = fmaxf(M, om);
    S = fmaf(S, __expf(M - mn), os * __expf(om - mn));
    M = mn;
  }
  out[r] = (float)Ai;
  ws[FIN_OFF + 2 * r]     = M;
  ws[FIN_OFF + 2 * r + 1] = 1.0f / S;
}

// ---------------- Kernel C: probs streaming (5 quads/thread, unrolled) -----
__global__ __launch_bounds__(ATHREADS, 4) void probs_kernel(
    const float* __restrict__ logits,
    const float* __restrict__ temps,
    const float* __restrict__ ws,
    float* __restrict__ out) {
  const uint32_t bx = blockIdx.x;
  const uint32_t b = bx / CHUNKS;
  const uint32_t chunk = bx - b * CHUNKS;
  const int tid = threadIdx.x;
  const float t = temps[b];
  const float inv_t = (t == 0.0f) ? 1.0f : (1.0f / t);
  const float M = ws[FIN_OFF + 2 * b];
  const float invS = ws[FIN_OFF + 2 * b + 1];
  const float* __restrict__ row = logits + (size_t)b * V_COLS;
  float* __restrict__ prow = out + B_ROWS + (size_t)b * V_COLS;
  const int q0 = (int)chunk * CHUNK_QUADS + tid;

#pragma unroll
  for (int j = 0; j < QPT; ++j) {
    const float4 x4 = reinterpret_cast<const float4*>(row)[q0 + j * ATHREADS];
    float4 p4;
    p4.x = __expf(fmaf(x4.x, inv_t, -M)) * invS;
    p4.y = __expf(fmaf(x4.y, inv_t, -M)) * invS;
    p4.z = __expf(fmaf(x4.z, inv_t, -M)) * invS;
    p4.w = __expf(fmaf(x4.w, inv_t, -M)) * invS;
    reinterpret_cast<float4*>(prow)[q0 + j * ATHREADS] = p4;
  }
}

extern "C" void kernel_launch(void* const* d_in, const int* in_sizes, int n_in,
                              void* d_out, int out_size, void* d_ws, size_t ws_size,
                              hipStream_t stream) {
  const float* logits = (const float*)d_in[0];
  const float* temps  = (const float*)d_in[1];
  float* out = (float*)d_out;
  float* ws  = (float*)d_ws;
  partial_kernel<<<B_ROWS * CHUNKS, ATHREADS, 0, stream>>>(logits, temps, ws);
  finalize_kernel<<<1, B_ROWS, 0, stream>>>(temps, ws, out);
  probs_kernel<<<B_ROWS * CHUNKS, ATHREADS, 0, stream>>>(logits, temps, ws, out);
}

// Round 7
// 110.482 us; speedup vs baseline: 1.2695x; 1.0825x over previous
//
#include <hip/hip_runtime.h>
#include <cstdint>
#include <cmath>

#define B_ROWS 256
#define V_COLS 128000
#define CHUNKS 25
#define CHUNK_QUADS 1280           // V_COLS/4/CHUNKS; exactly 5 quads/thread
#define ATHREADS 256
#define AWAVES 4
#define QPT 5
#define ELEMS_PT 20
#define LN2F 0.69314718055994530942f

// ws float layout:
//  G region:  [row][chunk][4] = (Gv, Gi, M, S)         @ 0,      25600 floats
//  FIN:       [row][4]        = (M, invS, Gi, unused)  @ 25600,   1024 floats
//  S region:  [row][chunk][2] = (Sv, Si)               @ 26624,  12800 floats
#define G_STRIDE 4
#define FIN_OFF (B_ROWS * CHUNKS * G_STRIDE)
#define S_OFF (FIN_OFF + B_ROWS * 4)

__device__ __forceinline__ uint32_t rotl32(uint32_t x, uint32_t d) {
  return __builtin_amdgcn_alignbit(x, x, 32u - d);
}

// threefry2x32 key (0,42), XOR of outputs (JAX partitionable threefry).
__device__ __forceinline__ uint32_t threefry_xor(uint32_t x0, uint32_t x1) {
  const uint32_t k0 = 0u;
  const uint32_t k1 = 42u;
  const uint32_t k2 = 0x1BD11BDAu ^ k0 ^ k1;
  x0 += k0; x1 += k1;
#define TF_RND(r) { x0 += x1; x1 = rotl32(x1, (r)); x1 ^= x0; }
  TF_RND(13) TF_RND(15) TF_RND(26) TF_RND(6)
  x0 += k1; x1 += k2 + 1u;
  TF_RND(17) TF_RND(29) TF_RND(16) TF_RND(24)
  x0 += k2; x1 += k0 + 2u;
  TF_RND(13) TF_RND(15) TF_RND(26) TF_RND(6)
  x0 += k0; x1 += k1 + 3u;
  TF_RND(17) TF_RND(29) TF_RND(16) TF_RND(24)
  x0 += k1; x1 += k2 + 4u;
  TF_RND(13) TF_RND(15) TF_RND(26) TF_RND(6)
  x0 += k2; x1 += k0 + 5u;
#undef TF_RND
  return x0 ^ x1;
}

// gumbel = -LN2F * gumbel_l2(bits); caller folds into fma with sx
__device__ __forceinline__ float gumbel_l2(uint32_t bits) {
  uint32_t ub = (bits >> 9) | 0x3f800000u;
  float f = __uint_as_float(ub) - 1.0f;
  float u = fmaxf(f, 1.17549435e-38f);
  const float l1 = __log2f(u);
  const float nl = -LN2F * l1;
  return __log2f(nl);
}

// ---------- K1: softmax (M,S) + greedy argmax partials (no RNG) ----------
__global__ __launch_bounds__(ATHREADS, 4) void pass1_kernel(
    const float* __restrict__ logits,
    const float* __restrict__ temps,
    float* __restrict__ ws) {
  const uint32_t bx = blockIdx.x;
  const uint32_t b = bx / CHUNKS;
  const uint32_t chunk = bx - b * CHUNKS;
  const int tid = threadIdx.x;
  const float t = temps[b];
  const float inv_t = (t == 0.0f) ? 1.0f : (1.0f / t);
  const float* __restrict__ row = logits + (size_t)b * V_COLS;
  const int q0 = (int)chunk * CHUNK_QUADS + tid;

  float4 xq[QPT];
#pragma unroll
  for (int j = 0; j < QPT; ++j)
    xq[j] = reinterpret_cast<const float4*>(row)[q0 + j * ATHREADS];

  float sx[ELEMS_PT];
#pragma unroll
  for (int j = 0; j < QPT; ++j) {
    sx[4 * j + 0] = xq[j].x * inv_t;
    sx[4 * j + 1] = xq[j].y * inv_t;
    sx[4 * j + 2] = xq[j].z * inv_t;
    sx[4 * j + 3] = xq[j].w * inv_t;
  }

  float mthr = sx[0];
#pragma unroll
  for (int k = 1; k < ELEMS_PT; ++k) mthr = fmaxf(mthr, sx[k]);
  float s = 0.0f;
#pragma unroll
  for (int k = 0; k < ELEMS_PT; ++k) s += __expf(sx[k] - mthr);

  // greedy argmax over raw x, strict > ascending => first index wins
  float av = -INFINITY; int ai = 0;
  const int v0 = q0 * 4;
#pragma unroll
  for (int j = 0; j < QPT; ++j) {
    const float xa[4] = {xq[j].x, xq[j].y, xq[j].z, xq[j].w};
#pragma unroll
    for (int k = 0; k < 4; ++k) {
      const bool up = xa[k] > av;
      av = up ? xa[k] : av;
      ai = up ? (v0 + j * 1024 + k) : ai;
    }
  }

  float m = mthr;
#pragma unroll
  for (int off = 32; off > 0; off >>= 1) {
    float ov = __shfl_xor(av, off);
    int   oi = __shfl_xor(ai, off);
    if (ov > av || (ov == av && oi < ai)) { av = ov; ai = oi; }
    float om = __shfl_xor(m, off);
    float os = __shfl_xor(s, off);
    float mn = fmaxf(m, om);
    s = fmaf(s, __expf(m - mn), os * __expf(om - mn));
    m = mn;
  }

  __shared__ float lds_av[AWAVES]; __shared__ int lds_ai[AWAVES];
  __shared__ float lds_m[AWAVES];  __shared__ float lds_s[AWAVES];
  const int wid = tid >> 6;
  if ((tid & 63) == 0) {
    lds_av[wid] = av; lds_ai[wid] = ai;
    lds_m[wid] = m;   lds_s[wid] = s;
  }
  __syncthreads();
  if (tid == 0) {
    float Av = lds_av[0]; int Ai = lds_ai[0];
    float M = lds_m[0];   float S = lds_s[0];
#pragma unroll
    for (int w = 1; w < AWAVES; ++w) {
      float ov = lds_av[w]; int oi = lds_ai[w];
      if (ov > Av || (ov == Av && oi < Ai)) { Av = ov; Ai = oi; }
      float om = lds_m[w]; float os = lds_s[w];
      float mn = fmaxf(M, om);
      S = fmaf(S, __expf(M - mn), os * __expf(om - mn));
      M = mn;
    }
    float* p = ws + (size_t)(b * CHUNKS + chunk) * G_STRIDE;
    p[0] = Av; p[1] = __int_as_float(Ai);
    p[2] = M;  p[3] = S;
  }
}

// ---------- K2: merge chunks -> per-row (M, invS, greedy idx) ----------
__global__ __launch_bounds__(B_ROWS) void fin1_kernel(
    float* __restrict__ ws) {
  const int r = threadIdx.x;
  const float* p = ws + (size_t)r * CHUNKS * G_STRIDE;
  float Av = -INFINITY; int Ai = 0;
  float M = -INFINITY;  float S = 0.0f;
#pragma unroll
  for (int c = 0; c < CHUNKS; ++c) {
    const float* q = p + c * G_STRIDE;
    float ov = q[0]; int oi = __float_as_int(q[1]);
    if (ov > Av) { Av = ov; Ai = oi; }   // ascending chunks: first index wins
    float om = q[2]; float os = q[3];
    float mn = fmaxf(M, om);
    S = fmaf(S, __expf(M - mn), os * __expf(om - mn));
    M = mn;
  }
  float* f = ws + FIN_OFF + 4 * r;
  f[0] = M;
  f[1] = 1.0f / S;
  f[2] = __int_as_float(Ai);
}

// ---------- K3: probs streaming + gumbel argmax partials (fused) ----------
__global__ __launch_bounds__(ATHREADS, 4) void pass2_kernel(
    const float* __restrict__ logits,
    const float* __restrict__ temps,
    float* __restrict__ ws,
    float* __restrict__ out) {
  const uint32_t bx = blockIdx.x;
  const uint32_t b = bx / CHUNKS;
  const uint32_t chunk = bx - b * CHUNKS;
  const int tid = threadIdx.x;
  const float t = temps[b];
  const float inv_t = (t == 0.0f) ? 1.0f : (1.0f / t);
  const float M = ws[FIN_OFF + 4 * b + 0];
  const float invS = ws[FIN_OFF + 4 * b + 1];
  const float* __restrict__ row = logits + (size_t)b * V_COLS;
  float* __restrict__ prow = out + B_ROWS + (size_t)b * V_COLS;
  const int q0 = (int)chunk * CHUNK_QUADS + tid;

  float4 xq[QPT];
#pragma unroll
  for (int j = 0; j < QPT; ++j)
    xq[j] = reinterpret_cast<const float4*>(row)[q0 + j * ATHREADS];

  // probs: memory-bound part, hides under the threefry VALU below
#pragma unroll
  for (int j = 0; j < QPT; ++j) {
    float4 p4;
    p4.x = __expf(fmaf(xq[j].x, inv_t, -M)) * invS;
    p4.y = __expf(fmaf(xq[j].y, inv_t, -M)) * invS;
    p4.z = __expf(fmaf(xq[j].z, inv_t, -M)) * invS;
    p4.w = __expf(fmaf(xq[j].w, inv_t, -M)) * invS;
    reinterpret_cast<float4*>(prow)[q0 + j * ATHREADS] = p4;
  }

  // gumbel argmax (exact R6 formulas; skipped entirely for t==0 rows)
  float av = -INFINITY; int ai = 0;
  if (t != 0.0f) {
    const int v0 = q0 * 4;
    const uint32_t cb = b * (uint32_t)V_COLS + (uint32_t)v0;
#pragma unroll
    for (int j = 0; j < QPT; ++j) {
      const float xa[4] = {xq[j].x, xq[j].y, xq[j].z, xq[j].w};
#pragma unroll
      for (int k = 0; k < 4; ++k) {
        const float sxv = xa[k] * inv_t;
        const float c = fmaf(-LN2F,
            gumbel_l2(threefry_xor(0u, cb + (uint32_t)(j * 1024 + k))), sxv);
        const bool up = c > av;
        av = up ? c : av;
        ai = up ? (v0 + j * 1024 + k) : ai;
      }
    }
  }

#pragma unroll
  for (int off = 32; off > 0; off >>= 1) {
    float ov = __shfl_xor(av, off);
    int   oi = __shfl_xor(ai, off);
    if (ov > av || (ov == av && oi < ai)) { av = ov; ai = oi; }
  }

  __shared__ float lds_av[AWAVES]; __shared__ int lds_ai[AWAVES];
  const int wid = tid >> 6;
  if ((tid & 63) == 0) { lds_av[wid] = av; lds_ai[wid] = ai; }
  __syncthreads();
  if (tid == 0) {
    float Av = lds_av[0]; int Ai = lds_ai[0];
#pragma unroll
    for (int w = 1; w < AWAVES; ++w) {
      float ov = lds_av[w]; int oi = lds_ai[w];
      if (ov > Av || (ov == Av && oi < Ai)) { Av = ov; Ai = oi; }
    }
    float* p = ws + S_OFF + (size_t)(b * CHUNKS + chunk) * 2;
    p[0] = Av; p[1] = __int_as_float(Ai);
  }
}

// ---------- K4: merge gumbel partials -> tokens ----------
__global__ __launch_bounds__(B_ROWS) void fin2_kernel(
    const float* __restrict__ temps,
    const float* __restrict__ ws,
    float* __restrict__ out) {
  const int r = threadIdx.x;
  const float t = temps[r];
  int token;
  if (t == 0.0f) {
    token = __float_as_int(ws[FIN_OFF + 4 * r + 2]);   // greedy
  } else {
    const float* p = ws + S_OFF + (size_t)r * CHUNKS * 2;
    float Sv = -INFINITY; int Si = 0;
#pragma unroll
    for (int c = 0; c < CHUNKS; ++c) {
      float ov = p[2 * c]; int oi = __float_as_int(p[2 * c + 1]);
      if (ov > Sv) { Sv = ov; Si = oi; }   // ascending: first index wins
    }
    token = Si;
  }
  out[r] = (float)token;
}

extern "C" void kernel_launch(void* const* d_in, const int* in_sizes, int n_in,
                              void* d_out, int out_size, void* d_ws, size_t ws_size,
                              hipStream_t stream) {
  const float* logits = (const float*)d_in[0];
  const float* temps  = (const float*)d_in[1];
  float* out = (float*)d_out;
  float* ws  = (float*)d_ws;
  pass1_kernel<<<B_ROWS * CHUNKS, ATHREADS, 0, stream>>>(logits, temps, ws);
  fin1_kernel<<<1, B_ROWS, 0, stream>>>(ws);
  pass2_kernel<<<B_ROWS * CHUNKS, ATHREADS, 0, stream>>>(logits, temps, ws, out);
  fin2_kernel<<<1, B_ROWS, 0, stream>>>(temps, ws, out);
}